// Round 14
// baseline (1264.231 us; speedup 1.0000x reference)
//
#include <hip/hip_runtime.h>
#include <type_traits>

// ---------------------------------------------------------------------------
// LLaDA Llama block, MI355X (gfx950). Round 14.
// vs R13: (a) gemm8p merged to 3 phases/tile (Q(1,0)+Q(1,1) share the a1
// read): 3 barriers + 3 lgkm0 per tile (was 4+4). Staging ledger: P1 stages
// A-h1(t+1) -> buf p^1 (region's last reader P3'(t-1), certified by that
// trailing barrier); P2 stages {A-h0,B-h0}(t+2); P3' stages B-h1(t+2);
// vmcnt(6) at tile end leaves exactly this tile's P2+P3' loads outstanding,
// so ALL of tile t+1 is certified at entry. Prologue: t0 full + t1 minus
// A-h1, vmcnt(6). (b) split-K epilogues fused into consumers: qk_addrope
// (add+rope on fp32 sums), v_addtrans (add fused into V transpose),
// rms_fuse (x+p0+p1 -> x2 and RMS-normed xn). add2bf/rope/add3(wo) removed.
// ---------------------------------------------------------------------------

#define D_MODEL 4096
#define FF_DIM  12288
#define SEQ     1024
#define NBATCH  2
#define M_ROWS  2048
#define NHEAD   32
#define HDIM    128
#define QKV_N   12288
#define FF2_N   24576

typedef short bf16x8 __attribute__((ext_vector_type(8)));
typedef ushort u16x16 __attribute__((ext_vector_type(16)));
typedef float f32x4  __attribute__((ext_vector_type(4)));

__device__ __forceinline__ ushort f2bf(float f) {
  unsigned u = __float_as_uint(f);
  u += 0x7FFFu + ((u >> 16) & 1u);
  return (ushort)(u >> 16);
}
__device__ __forceinline__ float bf2f(ushort u) {
  return __uint_as_float(((unsigned)u) << 16);
}

__device__ __forceinline__ void gload_lds16(const ushort* gsrc, ushort* ldst) {
  __builtin_amdgcn_global_load_lds((const __attribute__((address_space(1))) void*)gsrc,
                                   (__attribute__((address_space(3))) void*)ldst, 16, 0, 0);
}

#define SBAR()   asm volatile("s_barrier" ::: "memory")
#define LGKM0()  asm volatile("s_waitcnt lgkmcnt(0)" ::: "memory")
#define VMCNT6() asm volatile("s_waitcnt vmcnt(6)" ::: "memory")

// ---------------------------------------------------------------------------
// Weight convert+transpose: W (K x N, fp32) -> Wt (N x K, bf16), 64x64 tiles.
// remap!=0: FFN interleave, out-row = (n>>7)*256 + (n&127) + upoff.
// ---------------------------------------------------------------------------
__global__ __launch_bounds__(256)
void transpose_convert(const float* __restrict__ W, ushort* __restrict__ Wt,
                       int K, int N, int remap, int upoff)
{
  __shared__ float tile[64][68];
  const int t = threadIdx.x;
  const size_t k0 = (size_t)blockIdx.y * 64, n0 = (size_t)blockIdx.x * 64;
  const int lx = (t & 15) * 4, ly = t >> 4;     // load: 16 float4-cols x 16 rows
#pragma unroll
  for (int i = 0; i < 64; i += 16)
    *(float4*)&tile[ly + i][lx] = *(const float4*)&W[(k0 + ly + i) * N + n0 + lx];
  __syncthreads();
  const int n = t >> 2, kq = (t & 3) * 16;      // store: 64 n-rows x 4 k-chunks
  u16x16 ov;
#pragma unroll
  for (int e = 0; e < 16; e++) ov[e] = f2bf(tile[kq + e][n]);
  size_t nOut = n0 + n;
  if (remap) nOut = ((nOut >> 7) << 8) + (nOut & 127) + upoff;
  *(u16x16*)&Wt[nOut * K + k0 + kq] = ov;
}

// ---------------------------------------------------------------------------
// V add+transpose: vt[b,h,d,s] = p0.v + p1.v  (v cols of the qkv partials)
// ---------------------------------------------------------------------------
__global__ __launch_bounds__(256)
void v_addtrans(const ushort* __restrict__ p0, const ushort* __restrict__ p1,
                ushort* __restrict__ vt)
{
  __shared__ ushort tile[32][33];
  const int x = threadIdx.x, y = threadIdx.y;             // block (32,8)
  const int row0 = blockIdx.x * 32;
  const int d0 = blockIdx.y * 32;
  const int h = blockIdx.z;
  const int b = row0 >> 10, sl0 = row0 & (SEQ - 1);
#pragma unroll
  for (int i = 0; i < 32; i += 8) {
    const size_t idx = (size_t)(row0 + y + i) * QKV_N + 2 * D_MODEL + h * HDIM + d0 + x;
    tile[y + i][x] = f2bf(bf2f(p0[idx]) + bf2f(p1[idx]));
  }
  __syncthreads();
  ushort* ob = vt + ((size_t)(b * NHEAD + h) * HDIM + d0) * SEQ + sl0;
#pragma unroll
  for (int i = 0; i < 32; i += 8)
    ob[(size_t)(y + i) * SEQ + x] = tile[x][y + i];
}

// ---------------------------------------------------------------------------
// RMSNorm: row of 4096 fp32 -> bf16.  1 block (256 thr) per row.
// ---------------------------------------------------------------------------
__global__ __launch_bounds__(256)
void rmsnorm_kernel(const float* __restrict__ x, const float* __restrict__ w,
                    ushort* __restrict__ out)
{
  const int row = blockIdx.x, t = threadIdx.x;
  const float* xr = x + (size_t)row * D_MODEL;
  float4 vv[4];
  float ss = 0.f;
#pragma unroll
  for (int p = 0; p < 4; p++) {
    vv[p] = *(const float4*)&xr[p * 1024 + t * 4];
    ss += vv[p].x * vv[p].x + vv[p].y * vv[p].y + vv[p].z * vv[p].z + vv[p].w * vv[p].w;
  }
#pragma unroll
  for (int mm = 1; mm < 64; mm <<= 1) ss += __shfl_xor(ss, mm);
  __shared__ float wsum[4];
  if ((t & 63) == 0) wsum[t >> 6] = ss;
  __syncthreads();
  ss = wsum[0] + wsum[1] + wsum[2] + wsum[3];
  const float rs = rsqrtf(ss * (1.f / 4096.f) + 1e-5f);
#pragma unroll
  for (int p = 0; p < 4; p++) {
    const float4 wv = *(const float4*)&w[p * 1024 + t * 4];
    ushort4 ov;
    ov.x = f2bf(vv[p].x * rs * wv.x);
    ov.y = f2bf(vv[p].y * rs * wv.y);
    ov.z = f2bf(vv[p].z * rs * wv.z);
    ov.w = f2bf(vv[p].w * rs * wv.w);
    *(ushort4*)&out[(size_t)row * D_MODEL + p * 1024 + t * 4] = ov;
  }
}

// ---------------------------------------------------------------------------
// rms_fuse: x2 = x + p0 + p1 (fp32 out); xn = bf16(rmsnorm(x2) * w).
// 1 block per row; each thread handles 16 elems (2 chunks of 8).
// ---------------------------------------------------------------------------
__global__ __launch_bounds__(256)
void rms_fuse(const float* __restrict__ x, const ushort* __restrict__ p0,
              const ushort* __restrict__ p1, const float* __restrict__ w,
              float* __restrict__ x2, ushort* __restrict__ xn)
{
  const int row = blockIdx.x, t = threadIdx.x;
  const size_t rb = (size_t)row * D_MODEL;
  float s[2][8];
  float ss = 0.f;
#pragma unroll
  for (int c = 0; c < 2; c++) {
    const int base = c * 2048 + t * 8;
    const float4 xa = *(const float4*)&x[rb + base];
    const float4 xb = *(const float4*)&x[rb + base + 4];
    const bf16x8 a = *(const bf16x8*)&p0[rb + base];
    const bf16x8 b = *(const bf16x8*)&p1[rb + base];
    s[c][0] = xa.x + bf2f((ushort)a[0]) + bf2f((ushort)b[0]);
    s[c][1] = xa.y + bf2f((ushort)a[1]) + bf2f((ushort)b[1]);
    s[c][2] = xa.z + bf2f((ushort)a[2]) + bf2f((ushort)b[2]);
    s[c][3] = xa.w + bf2f((ushort)a[3]) + bf2f((ushort)b[3]);
    s[c][4] = xb.x + bf2f((ushort)a[4]) + bf2f((ushort)b[4]);
    s[c][5] = xb.y + bf2f((ushort)a[5]) + bf2f((ushort)b[5]);
    s[c][6] = xb.z + bf2f((ushort)a[6]) + bf2f((ushort)b[6]);
    s[c][7] = xb.w + bf2f((ushort)a[7]) + bf2f((ushort)b[7]);
    float4 o0 = {s[c][0], s[c][1], s[c][2], s[c][3]};
    float4 o1 = {s[c][4], s[c][5], s[c][6], s[c][7]};
    *(float4*)&x2[rb + base] = o0;
    *(float4*)&x2[rb + base + 4] = o1;
#pragma unroll
    for (int e = 0; e < 8; e++) ss += s[c][e] * s[c][e];
  }
#pragma unroll
  for (int mm = 1; mm < 64; mm <<= 1) ss += __shfl_xor(ss, mm);
  __shared__ float wsum[4];
  if ((t & 63) == 0) wsum[t >> 6] = ss;
  __syncthreads();
  ss = wsum[0] + wsum[1] + wsum[2] + wsum[3];
  const float rs = rsqrtf(ss * (1.f / 4096.f) + 1e-5f);
#pragma unroll
  for (int c = 0; c < 2; c++) {
    const int base = c * 2048 + t * 8;
    const float4 wa = *(const float4*)&w[base];
    const float4 wb = *(const float4*)&w[base + 4];
    ushort ov[8];
    ov[0] = f2bf(s[c][0] * rs * wa.x); ov[1] = f2bf(s[c][1] * rs * wa.y);
    ov[2] = f2bf(s[c][2] * rs * wa.z); ov[3] = f2bf(s[c][3] * rs * wa.w);
    ov[4] = f2bf(s[c][4] * rs * wb.x); ov[5] = f2bf(s[c][5] * rs * wb.y);
    ov[6] = f2bf(s[c][6] * rs * wb.z); ov[7] = f2bf(s[c][7] * rs * wb.w);
    *(bf16x8*)&xn[rb + base] = *(bf16x8*)ov;
  }
}

// ---------------------------------------------------------------------------
// qk_addrope: q/k = rope(p0 + p1) on fp32 sums, written bf16 into qkv buffer.
// One thread per (t, h, d<64).
// ---------------------------------------------------------------------------
__global__ __launch_bounds__(256)
void qk_addrope(const ushort* __restrict__ p0, const ushort* __restrict__ p1,
                ushort* __restrict__ qkv,
                const float* __restrict__ sinp, const float* __restrict__ cosp)
{
  const size_t idx = (size_t)blockIdx.x * 256 + threadIdx.x;   // < 2048*32*64
  const int d = (int)(idx & 63);
  const int h = (int)((idx >> 6) & 31);
  const int t = (int)(idx >> 11);
  const float s = sinp[t * 64 + d], c = cosp[t * 64 + d];
  const size_t qb = (size_t)t * QKV_N + h * HDIM + d;
  const size_t kb = qb + D_MODEL;
  const float q1 = bf2f(p0[qb])      + bf2f(p1[qb]);
  const float q2 = bf2f(p0[qb + 64]) + bf2f(p1[qb + 64]);
  qkv[qb]      = f2bf(q1 * c - q2 * s);
  qkv[qb + 64] = f2bf(q2 * c + q1 * s);
  const float k1 = bf2f(p0[kb])      + bf2f(p1[kb]);
  const float k2 = bf2f(p0[kb + 64]) + bf2f(p1[kb + 64]);
  qkv[kb]      = f2bf(k1 * c - k2 * s);
  qkv[kb + 64] = f2bf(k2 * c + k1 * s);
}

// ---------------------------------------------------------------------------
// Flash attention fwd. 1 wave per (b, h, 32-row Q pair). Deferred-max.
// ---------------------------------------------------------------------------
__global__ __launch_bounds__(64)
void attn_fwd(const ushort* __restrict__ q, const ushort* __restrict__ k,
              const ushort* __restrict__ vt, ushort* __restrict__ o,
              int ldq, int ldo)
{
  const int l = threadIdx.x, c16 = l & 15, g = l >> 4;
  const int qt = blockIdx.x, h = blockIdx.y, b = blockIdx.z;
  __shared__ __align__(16) ushort P_lds[2][16 * 32];

  const size_t head_off = (size_t)h * HDIM;
  const ushort* vtb = vt + (size_t)(b * NHEAD + h) * HDIM * SEQ;
  bf16x8 qf[2][4];
#pragma unroll
  for (int tile = 0; tile < 2; tile++) {
    const size_t rowQ = (size_t)(b * SEQ + qt * 32 + tile * 16 + c16);
#pragma unroll
    for (int kc = 0; kc < 4; kc++)
      qf[tile][kc] = *(const bf16x8*)(q + rowQ * ldq + head_off + kc * 32 + g * 8);
  }

  f32x4 oacc[2][8];
#pragma unroll
  for (int tile = 0; tile < 2; tile++)
#pragma unroll
    for (int i = 0; i < 8; i++) oacc[tile][i] = (f32x4){0.f, 0.f, 0.f, 0.f};
  float mrow[2][4], lsum[2][4];
#pragma unroll
  for (int tile = 0; tile < 2; tile++)
#pragma unroll
    for (int r = 0; r < 4; r++) { mrow[tile][r] = -1e30f; lsum[tile][r] = 0.f; }
  const float scale = 0.08838834764831845f;   // 1/sqrt(128)
  const float L2E = 1.4426950408889634f;

  for (int s0 = 0; s0 < SEQ; s0 += 32) {
    bf16x8 kfr[2][4];
#pragma unroll
    for (int t = 0; t < 2; t++) {
      const ushort* kb = k + (size_t)(b * SEQ + s0 + t * 16 + c16) * ldq + head_off + g * 8;
#pragma unroll
      for (int kc = 0; kc < 4; kc++) kfr[t][kc] = *(const bf16x8*)(kb + kc * 32);
    }
    f32x4 st[2][2];
#pragma unroll
    for (int tile = 0; tile < 2; tile++)
#pragma unroll
      for (int t = 0; t < 2; t++) {
        f32x4 a = (f32x4){0.f, 0.f, 0.f, 0.f};
#pragma unroll
        for (int kc = 0; kc < 4; kc++)
          a = __builtin_amdgcn_mfma_f32_16x16x32_bf16(qf[tile][kc], kfr[t][kc], a, 0, 0, 0);
        st[tile][t] = a;
      }

    float s0v[2][4], s1v[2][4];
    float worst = -1e30f;
#pragma unroll
    for (int tile = 0; tile < 2; tile++)
#pragma unroll
      for (int r = 0; r < 4; r++) {
        s0v[tile][r] = st[tile][0][r] * scale;
        s1v[tile][r] = st[tile][1][r] * scale;
        worst = fmaxf(worst, fmaxf(s0v[tile][r], s1v[tile][r]) - mrow[tile][r]);
      }

    if (__any(worst > 8.0f)) {
#pragma unroll
      for (int tile = 0; tile < 2; tile++) {
        float a4[4];
#pragma unroll
        for (int r = 0; r < 4; r++) {
          float cm = fmaxf(s0v[tile][r], s1v[tile][r]);
#pragma unroll
          for (int mm = 1; mm < 16; mm <<= 1) cm = fmaxf(cm, __shfl_xor(cm, mm));
          const float mn = fmaxf(mrow[tile][r], cm);
          a4[r] = exp2f((mrow[tile][r] - mn) * L2E);
          mrow[tile][r] = mn;
          const float p0 = exp2f((s0v[tile][r] - mn) * L2E);
          const float p1 = exp2f((s1v[tile][r] - mn) * L2E);
          lsum[tile][r] = lsum[tile][r] * a4[r] + p0 + p1;
          P_lds[tile][(g * 4 + r) * 32 + c16]      = f2bf(p0);
          P_lds[tile][(g * 4 + r) * 32 + 16 + c16] = f2bf(p1);
        }
        const f32x4 av = (f32x4){a4[0], a4[1], a4[2], a4[3]};
#pragma unroll
        for (int dbi = 0; dbi < 8; dbi++) oacc[tile][dbi] *= av;
      }
    } else {
#pragma unroll
      for (int tile = 0; tile < 2; tile++)
#pragma unroll
        for (int r = 0; r < 4; r++) {
          const float p0 = exp2f((s0v[tile][r] - mrow[tile][r]) * L2E);
          const float p1 = exp2f((s1v[tile][r] - mrow[tile][r]) * L2E);
          lsum[tile][r] += p0 + p1;
          P_lds[tile][(g * 4 + r) * 32 + c16]      = f2bf(p0);
          P_lds[tile][(g * 4 + r) * 32 + 16 + c16] = f2bf(p1);
        }
    }
    __syncthreads();
    const bf16x8 pf0 = *(const bf16x8*)&P_lds[0][c16 * 32 + g * 8];
    const bf16x8 pf1 = *(const bf16x8*)&P_lds[1][c16 * 32 + g * 8];
#pragma unroll
    for (int dbi = 0; dbi < 8; dbi++) {
      const bf16x8 vf = *(const bf16x8*)(vtb + (size_t)(dbi * 16 + c16) * SEQ + s0 + g * 8);
      oacc[0][dbi] = __builtin_amdgcn_mfma_f32_16x16x32_bf16(pf0, vf, oacc[0][dbi], 0, 0, 0);
      oacc[1][dbi] = __builtin_amdgcn_mfma_f32_16x16x32_bf16(pf1, vf, oacc[1][dbi], 0, 0, 0);
    }
    __syncthreads();
  }

#pragma unroll
  for (int tile = 0; tile < 2; tile++)
#pragma unroll
    for (int r = 0; r < 4; r++) {
#pragma unroll
      for (int mm = 1; mm < 16; mm <<= 1)
        lsum[tile][r] += __shfl_xor(lsum[tile][r], mm);
    }
#pragma unroll
  for (int tile = 0; tile < 2; tile++) {
    const size_t rowO = (size_t)(b * SEQ + qt * 32 + tile * 16 + g * 4);
#pragma unroll
    for (int dbi = 0; dbi < 8; dbi++)
#pragma unroll
      for (int r = 0; r < 4; r++)
        o[(rowO + r) * ldo + head_off + dbi * 16 + c16] =
            f2bf(oacc[tile][dbi][r] / lsum[tile][r]);
  }
}

// ---------------------------------------------------------------------------
// add3bf: d(fp32) = a(fp32) + p0(bf16) + p1(bf16).  Final out epilogue.
// ---------------------------------------------------------------------------
__global__ __launch_bounds__(256)
void add3bf_kernel(const float* __restrict__ a, const ushort* __restrict__ p0,
                   const ushort* __restrict__ p1, float* __restrict__ d, int n8)
{
  for (int i = blockIdx.x * 256 + threadIdx.x; i < n8; i += gridDim.x * 256) {
    const float4 a0 = ((const float4*)a)[i * 2];
    const float4 a1 = ((const float4*)a)[i * 2 + 1];
    const bf16x8 b = *(const bf16x8*)&p0[(size_t)i * 8];
    const bf16x8 c = *(const bf16x8*)&p1[(size_t)i * 8];
    float4 d0, d1;
    d0.x = a0.x + bf2f((ushort)b[0]) + bf2f((ushort)c[0]);
    d0.y = a0.y + bf2f((ushort)b[1]) + bf2f((ushort)c[1]);
    d0.z = a0.z + bf2f((ushort)b[2]) + bf2f((ushort)c[2]);
    d0.w = a0.w + bf2f((ushort)b[3]) + bf2f((ushort)c[3]);
    d1.x = a1.x + bf2f((ushort)b[4]) + bf2f((ushort)c[4]);
    d1.y = a1.y + bf2f((ushort)b[5]) + bf2f((ushort)c[5]);
    d1.z = a1.z + bf2f((ushort)b[6]) + bf2f((ushort)c[6]);
    d1.w = a1.w + bf2f((ushort)b[7]) + bf2f((ushort)c[7]);
    ((float4*)d)[i * 2]     = d0;
    ((float4*)d)[i * 2 + 1] = d1;
  }
}

// ---------------------------------------------------------------------------
// 256x256 GEMM, 3 phases/tile (16x16x32 MFMA, folded ds_read addressing).
// Tile t (parity P):
//  P1: rd b0(4)+a0(8); STG A-h1(t+1)->P^1;       LGKM0; 16 MFMA Q(0,0); SBAR
//  P2: rd b1(4);       STG {A-h0,B-h0}(t+2)->P;  LGKM0; 16 MFMA Q(0,1); SBAR
//  P3: rd a1(8);       STG {B-h1}(t+2)->P;       LGKM0; 32 MFMA Q(1,*);
//      VMCNT6; SBAR
// vmcnt(6) at tile end: outstanding = this tile's P2(4)+P3(2) -> retires
// P1's A-h1(t+1) and all older => tile t+1 fully certified at entry.
// WAR: each staged region's last reader finished before the preceding
// trailing barrier (A-h1(P^1): P3(t-1); A-h0/B-h0(P): P1(t); B-h1(P): P2(t)).
// EPI 0: bf16 | 1: fp32 res+acc | 2: fused SwiGLU | 4: bf16 split-K partial.
// ---------------------------------------------------------------------------
template <int EPI, bool SPLITK>
__global__ __launch_bounds__(512, 2)
void gemm8p(const ushort* __restrict__ A, const ushort* __restrict__ Bt,
            const float* __restrict__ res, void* __restrict__ Cout,
            int M, int N, int Ks, int ldk, int wps)
{
  __shared__ __align__(16) ushort lds[65536];   // 128 KB
  const int tid = threadIdx.x;
  const int w = tid >> 6, l = tid & 63;
  const int c16 = l & 15, g = l >> 4;
  const int wr = w >> 2, wc = w & 3;

  // T1 bijective XCD remap (m204), then (optional) split-K, then 2D chunk
  const int nwg = gridDim.x;
  const int q8 = nwg >> 3, r8 = nwg & 7;
  const int xcd = blockIdx.x & 7, loc = blockIdx.x >> 3;
  int wg = (xcd < r8 ? xcd * (q8 + 1) : r8 * (q8 + 1) + (xcd - r8) * q8) + loc;
  int kslice = 0;
  if constexpr (SPLITK) { kslice = wg / wps; wg -= kslice * wps; }
  const size_t m0 = (size_t)(wg & 7) * 256;
  const size_t n0 = (size_t)(wg >> 3) * 256;
  const int nk = Ks >> 6;

  const int srow  = (w << 3) + (l >> 3);
  const int scolE = ((l & 7) ^ (l >> 3)) << 3;        // swizzled source col
  const ushort* gA = A  + (size_t)kslice * Ks + (m0 + srow) * (size_t)ldk + scolE;
  const ushort* gB = Bt + (size_t)kslice * Ks + (n0 + srow) * (size_t)ldk + scolE;

#define STG_A(p, h, q, tk)                                                        \
  gload_lds16(gA + (size_t)((h) * 128 + (q) * 64) * ldk + (size_t)(tk) * 64,      \
              lds + (p) * 16384 + (h) * 8192 + (q) * 4096 + (w << 9))
#define STG_B(p, h, q, tk)                                                        \
  gload_lds16(gB + (size_t)((h) * 128 + (q) * 64) * ldk + (size_t)(tk) * 64,      \
              lds + 32768 + (p) * 16384 + (h) * 8192 + (q) * 4096 + (w << 9))
#define STG_A2(p, h, tk) do { STG_A(p, h, 0, tk); STG_A(p, h, 1, tk); } while (0)
#define STG_B2(p, h, tk) do { STG_B(p, h, 0, tk); STG_B(p, h, 1, tk); } while (0)

  const int xorE = (c16 & 7) << 3;
  const int k0E = (g * 8) ^ xorE;
  const int k1E = (32 + g * 8) ^ xorE;
  const int aRow = wr * 64 + c16;
  const int bRow = wc * 32 + c16;

  const char* ldsb = (const char*)lds;
  const char* pA0 = ldsb + aRow * 128 + k0E * 2;
  const char* pA1 = ldsb + aRow * 128 + k1E * 2;
  const char* pB0 = ldsb + 65536 + bRow * 128 + k0E * 2;
  const char* pB1 = ldsb + 65536 + bRow * 128 + k1E * 2;

#define RDA(P, qm, i, kk)                                                         \
  (*(const bf16x8*)((kk ? pA1 : pA0) + (P) * 32768 + (qm) * 16384 + (i) * 2048))
#define RDB(P, qn, j, kk)                                                         \
  (*(const bf16x8*)((kk ? pB1 : pB0) + (P) * 32768 + (qn) * 16384 + (j) * 2048))

  f32x4 acc[8][4];
#pragma unroll
  for (int i = 0; i < 8; i++)
#pragma unroll
    for (int j = 0; j < 4; j++) acc[i][j] = (f32x4){0.f, 0.f, 0.f, 0.f};
  bf16x8 a[4][2], b0[2][2], b1[2][2];

  // prologue: tile 0 complete (8 loads), tile 1 minus A-h1 (6 loads)
  STG_A2(0, 0, 0); STG_A2(0, 1, 0); STG_B2(0, 0, 0); STG_B2(0, 1, 0);
  STG_A2(1, 0, 1); STG_B2(1, 0, 1); STG_B2(1, 1, 1);
  VMCNT6(); SBAR();

  auto tileBody = [&](auto Pc, int t) {
    constexpr int P = decltype(Pc)::value;
    const int tn1 = (t + 1 < nk) ? t + 1 : 0;             // wrap: garbage, never read
    const int tn2 = (t + 2 < nk) ? t + 2 : t + 2 - nk;

    // ---- phase 1: Q(0,0); stage A-h1(t+1) -> buf P^1
#pragma unroll
    for (int j = 0; j < 2; ++j) { b0[j][0] = RDB(P, 0, j, 0); b0[j][1] = RDB(P, 0, j, 1); }
#pragma unroll
    for (int i = 0; i < 4; ++i) { a[i][0] = RDA(P, 0, i, 0); a[i][1] = RDA(P, 0, i, 1); }
    STG_A2(P ^ 1, 1, tn1);
    LGKM0();
    __builtin_amdgcn_s_setprio(1);
#pragma unroll
    for (int i = 0; i < 4; ++i)
#pragma unroll
      for (int j = 0; j < 2; ++j)
#pragma unroll
        for (int kk = 0; kk < 2; ++kk)
          acc[i][j] = __builtin_amdgcn_mfma_f32_16x16x32_bf16(a[i][kk], b0[j][kk], acc[i][j], 0, 0, 0);
    __builtin_amdgcn_s_setprio(0);
    SBAR();

    // ---- phase 2: Q(0,1); stage {A-h0, B-h0}(t+2) -> buf P
#pragma unroll
    for (int j = 0; j < 2; ++j) { b1[j][0] = RDB(P, 1, j, 0); b1[j][1] = RDB(P, 1, j, 1); }
    STG_A2(P, 0, tn2);
    STG_B2(P, 0, tn2);
    LGKM0();
    __builtin_amdgcn_s_setprio(1);
#pragma unroll
    for (int i = 0; i < 4; ++i)
#pragma unroll
      for (int j = 0; j < 2; ++j)
#pragma unroll
        for (int kk = 0; kk < 2; ++kk)
          acc[i][2 + j] = __builtin_amdgcn_mfma_f32_16x16x32_bf16(a[i][kk], b1[j][kk], acc[i][2 + j], 0, 0, 0);
    __builtin_amdgcn_s_setprio(0);
    SBAR();

    // ---- phase 3: Q(1,0)+Q(1,1); stage {B-h1}(t+2) -> buf P; vmcnt(6)
#pragma unroll
    for (int i = 0; i < 4; ++i) { a[i][0] = RDA(P, 1, i, 0); a[i][1] = RDA(P, 1, i, 1); }
    STG_B2(P, 1, tn2);
    LGKM0();
    __builtin_amdgcn_s_setprio(1);
#pragma unroll
    for (int i = 0; i < 4; ++i)
#pragma unroll
      for (int j = 0; j < 2; ++j)
#pragma unroll
        for (int kk = 0; kk < 2; ++kk)
          acc[4 + i][j] = __builtin_amdgcn_mfma_f32_16x16x32_bf16(a[i][kk], b0[j][kk], acc[4 + i][j], 0, 0, 0);
#pragma unroll
    for (int i = 0; i < 4; ++i)
#pragma unroll
      for (int j = 0; j < 2; ++j)
#pragma unroll
        for (int kk = 0; kk < 2; ++kk)
          acc[4 + i][2 + j] = __builtin_amdgcn_mfma_f32_16x16x32_bf16(a[i][kk], b1[j][kk], acc[4 + i][2 + j], 0, 0, 0);
    __builtin_amdgcn_s_setprio(0);
    VMCNT6(); SBAR();
  };

  for (int t = 0; t < nk; t += 2) {                      // nk always even here
    tileBody(std::integral_constant<int, 0>{}, t);
    tileBody(std::integral_constant<int, 1>{}, t + 1);
  }

  // epilogue
#pragma unroll
  for (int qm = 0; qm < 2; qm++)
#pragma unroll
    for (int i = 0; i < 4; i++)
#pragma unroll
      for (int qn = 0; qn < 2; qn++)
#pragma unroll
        for (int j = 0; j < 2; j++)
#pragma unroll
          for (int r = 0; r < 4; r++) {
            const size_t row = m0 + qm * 128 + wr * 64 + i * 16 + g * 4 + r;
            if constexpr (EPI == 2) {
              if (qn == 1) continue;           // handled with qn==0 pair
              const float hv = acc[qm * 4 + i][j][r];
              const float uv = acc[qm * 4 + i][2 + j][r];
              const size_t col = (n0 >> 1) + wc * 32 + j * 16 + c16;
              ((ushort*)Cout)[row * (size_t)(N >> 1) + col] =
                  f2bf((hv / (1.f + __expf(-hv))) * uv);
            } else {
              const size_t col = n0 + qn * 128 + wc * 32 + j * 16 + c16;
              const size_t idx = row * N + col;
              const float v = acc[qm * 4 + i][qn * 2 + j][r];
              if constexpr (EPI == 0)      ((ushort*)Cout)[idx] = f2bf(v);
              else if constexpr (EPI == 1) ((float*)Cout)[idx] = res[idx] + v;
              else                         ((ushort*)Cout)[(size_t)kslice * M * N + idx] = f2bf(v);
            }
          }
#undef STG_A
#undef STG_B
#undef STG_A2
#undef STG_B2
#undef RDA
#undef RDB
}

// ---------------------------------------------------------------------------
extern "C" void kernel_launch(void* const* d_in, const int* in_sizes, int n_in,
                              void* d_out, int out_size, void* d_ws, size_t ws_size,
                              hipStream_t stream)
{
  const float* x    = (const float*)d_in[0];
  const float* sinp = (const float*)d_in[1];
  const float* cosp = (const float*)d_in[2];
  const float* anw  = (const float*)d_in[3];
  const float* fnw  = (const float*)d_in[4];
  const float* wq   = (const float*)d_in[5];
  const float* wk   = (const float*)d_in[6];
  const float* wv   = (const float*)d_in[7];
  const float* wo   = (const float*)d_in[8];
  const float* wff  = (const float*)d_in[9];
  const float* wup  = (const float*)d_in[10];
  const float* wout = (const float*)d_in[11];
  float* out = (float*)d_out;

  const size_t szDD   = (size_t)D_MODEL * D_MODEL * 2;
  const size_t szDF   = (size_t)D_MODEL * FF_DIM * 2;
  const size_t szAct2 = (size_t)M_ROWS * D_MODEL * 2;
  const size_t szAct4 = (size_t)M_ROWS * D_MODEL * 4;
  const size_t szQKV  = (size_t)M_ROWS * QKV_N * 2;
  const size_t MN     = (size_t)M_ROWS * D_MODEL;
  const size_t MNq    = (size_t)M_ROWS * QKV_N;

  char* ws = (char*)d_ws;
  size_t off = 0;
  auto alloc = [&](size_t bytes) -> char* {
    char* p = ws + off;
    off += (bytes + 255) & ~(size_t)255;
    return p;
  };
  ushort* R1    = (ushort*)alloc(szDF);     // wq|wk|wv^T, later wout^T
  ushort* R2    = (ushort*)alloc(2 * szDF); // qkv bf16 partials, then wff|wup panels
  ushort* wot   = (ushort*)alloc(szDD);
  ushort* xn    = (ushort*)alloc(szAct2);
  ushort* qkv   = (ushort*)alloc(szQKV);    // q,k roped; later reused as g
  ushort* attnb = (ushort*)alloc(szAct2);
  float*  x2    = (float*)alloc(szAct4);
  ushort* vtb   = (ushort*)alloc(szAct2);   // V^T [b,h,d,s]
  ushort* partb = (ushort*)alloc(2 * MN * 2); // bf16 split-K partials (N=4096 GEMMs)
  if (off > ws_size) return;                // visible failure, no corruption

  // attn-branch weights first (R2 is qkv-partial scratch until wff/wup convert)
  transpose_convert<<<dim3(D_MODEL / 64, D_MODEL / 64), 256, 0, stream>>>(wq, R1, D_MODEL, D_MODEL, 0, 0);
  transpose_convert<<<dim3(D_MODEL / 64, D_MODEL / 64), 256, 0, stream>>>(wk, R1 + (size_t)D_MODEL * D_MODEL, D_MODEL, D_MODEL, 0, 0);
  transpose_convert<<<dim3(D_MODEL / 64, D_MODEL / 64), 256, 0, stream>>>(wv, R1 + 2 * (size_t)D_MODEL * D_MODEL, D_MODEL, D_MODEL, 0, 0);
  transpose_convert<<<dim3(D_MODEL / 64, D_MODEL / 64), 256, 0, stream>>>(wo, wot, D_MODEL, D_MODEL, 0, 0);

  // attn branch
  rmsnorm_kernel<<<M_ROWS, 256, 0, stream>>>(x, anw, xn);
  // qkv GEMM: split-K x2 (Ks=2048), grid 768 = 3 full rounds; bf16 partials in R2
  ushort* qpart = R2;
  gemm8p<4, true><<<2 * (M_ROWS / 256) * (QKV_N / 256), 512, 0, stream>>>(
      xn, R1, nullptr, qpart, M_ROWS, QKV_N, D_MODEL / 2, D_MODEL,
      (M_ROWS / 256) * (QKV_N / 256));
  // fused epilogues consume the partials directly
  qk_addrope<<<(M_ROWS * NHEAD * 64) / 256, 256, 0, stream>>>(qpart, qpart + MNq, qkv, sinp, cosp);
  v_addtrans<<<dim3(M_ROWS / 32, HDIM / 32, NHEAD), dim3(32, 8), 0, stream>>>(qpart, qpart + MNq, vtb);

  // ffn weights now (R2 free again), wout into R1 (free after qkv GEMM)
  transpose_convert<<<dim3(FF_DIM / 64, D_MODEL / 64), 256, 0, stream>>>(wff, R2, D_MODEL, FF_DIM, 1, 0);
  transpose_convert<<<dim3(FF_DIM / 64, D_MODEL / 64), 256, 0, stream>>>(wup, R2, D_MODEL, FF_DIM, 1, 128);
  transpose_convert<<<dim3(D_MODEL / 64, FF_DIM / 64), 256, 0, stream>>>(wout, R1, FF_DIM, D_MODEL, 0, 0);

  attn_fwd<<<dim3(SEQ / 32, NHEAD, NBATCH), 64, 0, stream>>>(qkv, qkv + D_MODEL, vtb, attnb, QKV_N, D_MODEL);
  // wo GEMM: split-K x2 (Ks=2048), bf16 partials -> rms_fuse makes x2 and xn
  gemm8p<4, true><<<256, 512, 0, stream>>>(attnb, wot, nullptr, partb, M_ROWS, D_MODEL, D_MODEL / 2, D_MODEL, 128);
  rms_fuse<<<M_ROWS, 256, 0, stream>>>(x, partb, partb + MN, fnw, x2, xn);

  // ffn branch (SwiGLU fused into GEMM epilogue; g written into qkv buffer)
  gemm8p<2, false><<<(M_ROWS / 256) * (FF2_N / 256), 512, 0, stream>>>(xn, R2, nullptr, qkv /* g */, M_ROWS, FF2_N, D_MODEL, D_MODEL, 0);
  // out GEMM: split-K x2 (Ks=6144), bf16 partials -> out = x2 + p0 + p1
  gemm8p<4, true><<<256, 512, 0, stream>>>(qkv, R1, nullptr, partb, M_ROWS, D_MODEL, FF_DIM / 2, FF_DIM, 128);
  add3bf_kernel<<<2048, 256, 0, stream>>>(x2, partb, partb + MN, out, (int)(MN / 8));
}

// Round 15
// 1251.509 us; speedup vs baseline: 1.0102x; 1.0102x over previous
//
#include <hip/hip_runtime.h>
#include <type_traits>

// ---------------------------------------------------------------------------
// LLaDA Llama block, MI355X (gfx950). Round 15 (consolidation).
// vs R14: (a) weight conversions merged: conv_dd (wq/wk/wv/wo via blockIdx.z)
// and conv_ffup (wff/wup via z) — 7 -> 4 conversion launches; (b) gemm8p
// phases issue the global_load_lds staging BEFORE the ds_reads (earlier DMA
// issue; LGKM0 waits lgkm only, vmcnt ledger unchanged). GEMM core otherwise
// identical to R14 (verified: 3-phase, vmcnt(6), 54.6% MfmaUtil).
// ---------------------------------------------------------------------------

#define D_MODEL 4096
#define FF_DIM  12288
#define SEQ     1024
#define NBATCH  2
#define M_ROWS  2048
#define NHEAD   32
#define HDIM    128
#define QKV_N   12288
#define FF2_N   24576

typedef short bf16x8 __attribute__((ext_vector_type(8)));
typedef ushort u16x16 __attribute__((ext_vector_type(16)));
typedef float f32x4  __attribute__((ext_vector_type(4)));

__device__ __forceinline__ ushort f2bf(float f) {
  unsigned u = __float_as_uint(f);
  u += 0x7FFFu + ((u >> 16) & 1u);
  return (ushort)(u >> 16);
}
__device__ __forceinline__ float bf2f(ushort u) {
  return __uint_as_float(((unsigned)u) << 16);
}

__device__ __forceinline__ void gload_lds16(const ushort* gsrc, ushort* ldst) {
  __builtin_amdgcn_global_load_lds((const __attribute__((address_space(1))) void*)gsrc,
                                   (__attribute__((address_space(3))) void*)ldst, 16, 0, 0);
}

#define SBAR()   asm volatile("s_barrier" ::: "memory")
#define LGKM0()  asm volatile("s_waitcnt lgkmcnt(0)" ::: "memory")
#define VMCNT6() asm volatile("s_waitcnt vmcnt(6)" ::: "memory")

// ---------------------------------------------------------------------------
// Transpose+convert core: W (K x N fp32) tile -> Wt (N x K bf16).
// ---------------------------------------------------------------------------
__device__ __forceinline__ void tc_body(const float* __restrict__ W,
                                        ushort* __restrict__ Wt,
                                        int K, int N, int remap, int upoff,
                                        int bx, int by)
{
  __shared__ float tile[64][68];
  const int t = threadIdx.x;
  const size_t k0 = (size_t)by * 64, n0 = (size_t)bx * 64;
  const int lx = (t & 15) * 4, ly = t >> 4;
#pragma unroll
  for (int i = 0; i < 64; i += 16)
    *(float4*)&tile[ly + i][lx] = *(const float4*)&W[(k0 + ly + i) * N + n0 + lx];
  __syncthreads();
  const int n = t >> 2, kq = (t & 3) * 16;
  u16x16 ov;
#pragma unroll
  for (int e = 0; e < 16; e++) ov[e] = f2bf(tile[kq + e][n]);
  size_t nOut = n0 + n;
  if (remap) nOut = ((nOut >> 7) << 8) + (nOut & 127) + upoff;
  *(u16x16*)&Wt[nOut * K + k0 + kq] = ov;
}

// 4 D x D weights in one launch (z = 0..3)
__global__ __launch_bounds__(256)
void conv_dd(const float* __restrict__ w0, const float* __restrict__ w1,
             const float* __restrict__ w2, const float* __restrict__ w3,
             ushort* __restrict__ d012, ushort* __restrict__ d3)
{
  const int z = blockIdx.z;
  const float* src = (z == 0) ? w0 : (z == 1) ? w1 : (z == 2) ? w2 : w3;
  ushort* dst = (z < 3) ? d012 + (size_t)z * D_MODEL * D_MODEL : d3;
  tc_body(src, dst, D_MODEL, D_MODEL, 0, 0, blockIdx.x, blockIdx.y);
}

// wff / wup interleaved into one buffer (z = 0..1)
__global__ __launch_bounds__(256)
void conv_ffup(const float* __restrict__ wff, const float* __restrict__ wup,
               ushort* __restrict__ dst)
{
  const int z = blockIdx.z;
  tc_body(z ? wup : wff, dst, D_MODEL, FF_DIM, 1, z * 128, blockIdx.x, blockIdx.y);
}

// generic single-weight version (wout)
__global__ __launch_bounds__(256)
void transpose_convert(const float* __restrict__ W, ushort* __restrict__ Wt,
                       int K, int N)
{
  tc_body(W, Wt, K, N, 0, 0, blockIdx.x, blockIdx.y);
}

// ---------------------------------------------------------------------------
// V add+transpose: vt[b,h,d,s] = p0.v + p1.v  (v cols of the qkv partials)
// ---------------------------------------------------------------------------
__global__ __launch_bounds__(256)
void v_addtrans(const ushort* __restrict__ p0, const ushort* __restrict__ p1,
                ushort* __restrict__ vt)
{
  __shared__ ushort tile[32][33];
  const int x = threadIdx.x, y = threadIdx.y;             // block (32,8)
  const int row0 = blockIdx.x * 32;
  const int d0 = blockIdx.y * 32;
  const int h = blockIdx.z;
  const int b = row0 >> 10, sl0 = row0 & (SEQ - 1);
#pragma unroll
  for (int i = 0; i < 32; i += 8) {
    const size_t idx = (size_t)(row0 + y + i) * QKV_N + 2 * D_MODEL + h * HDIM + d0 + x;
    tile[y + i][x] = f2bf(bf2f(p0[idx]) + bf2f(p1[idx]));
  }
  __syncthreads();
  ushort* ob = vt + ((size_t)(b * NHEAD + h) * HDIM + d0) * SEQ + sl0;
#pragma unroll
  for (int i = 0; i < 32; i += 8)
    ob[(size_t)(y + i) * SEQ + x] = tile[x][y + i];
}

// ---------------------------------------------------------------------------
// RMSNorm: row of 4096 fp32 -> bf16.  1 block (256 thr) per row.
// ---------------------------------------------------------------------------
__global__ __launch_bounds__(256)
void rmsnorm_kernel(const float* __restrict__ x, const float* __restrict__ w,
                    ushort* __restrict__ out)
{
  const int row = blockIdx.x, t = threadIdx.x;
  const float* xr = x + (size_t)row * D_MODEL;
  float4 vv[4];
  float ss = 0.f;
#pragma unroll
  for (int p = 0; p < 4; p++) {
    vv[p] = *(const float4*)&xr[p * 1024 + t * 4];
    ss += vv[p].x * vv[p].x + vv[p].y * vv[p].y + vv[p].z * vv[p].z + vv[p].w * vv[p].w;
  }
#pragma unroll
  for (int mm = 1; mm < 64; mm <<= 1) ss += __shfl_xor(ss, mm);
  __shared__ float wsum[4];
  if ((t & 63) == 0) wsum[t >> 6] = ss;
  __syncthreads();
  ss = wsum[0] + wsum[1] + wsum[2] + wsum[3];
  const float rs = rsqrtf(ss * (1.f / 4096.f) + 1e-5f);
#pragma unroll
  for (int p = 0; p < 4; p++) {
    const float4 wv = *(const float4*)&w[p * 1024 + t * 4];
    ushort4 ov;
    ov.x = f2bf(vv[p].x * rs * wv.x);
    ov.y = f2bf(vv[p].y * rs * wv.y);
    ov.z = f2bf(vv[p].z * rs * wv.z);
    ov.w = f2bf(vv[p].w * rs * wv.w);
    *(ushort4*)&out[(size_t)row * D_MODEL + p * 1024 + t * 4] = ov;
  }
}

// ---------------------------------------------------------------------------
// rms_fuse: x2 = x + p0 + p1 (fp32 out); xn = bf16(rmsnorm(x2) * w).
// ---------------------------------------------------------------------------
__global__ __launch_bounds__(256)
void rms_fuse(const float* __restrict__ x, const ushort* __restrict__ p0,
              const ushort* __restrict__ p1, const float* __restrict__ w,
              float* __restrict__ x2, ushort* __restrict__ xn)
{
  const int row = blockIdx.x, t = threadIdx.x;
  const size_t rb = (size_t)row * D_MODEL;
  float s[2][8];
  float ss = 0.f;
#pragma unroll
  for (int c = 0; c < 2; c++) {
    const int base = c * 2048 + t * 8;
    const float4 xa = *(const float4*)&x[rb + base];
    const float4 xb = *(const float4*)&x[rb + base + 4];
    const bf16x8 a = *(const bf16x8*)&p0[rb + base];
    const bf16x8 b = *(const bf16x8*)&p1[rb + base];
    s[c][0] = xa.x + bf2f((ushort)a[0]) + bf2f((ushort)b[0]);
    s[c][1] = xa.y + bf2f((ushort)a[1]) + bf2f((ushort)b[1]);
    s[c][2] = xa.z + bf2f((ushort)a[2]) + bf2f((ushort)b[2]);
    s[c][3] = xa.w + bf2f((ushort)a[3]) + bf2f((ushort)b[3]);
    s[c][4] = xb.x + bf2f((ushort)a[4]) + bf2f((ushort)b[4]);
    s[c][5] = xb.y + bf2f((ushort)a[5]) + bf2f((ushort)b[5]);
    s[c][6] = xb.z + bf2f((ushort)a[6]) + bf2f((ushort)b[6]);
    s[c][7] = xb.w + bf2f((ushort)a[7]) + bf2f((ushort)b[7]);
    float4 o0 = {s[c][0], s[c][1], s[c][2], s[c][3]};
    float4 o1 = {s[c][4], s[c][5], s[c][6], s[c][7]};
    *(float4*)&x2[rb + base] = o0;
    *(float4*)&x2[rb + base + 4] = o1;
#pragma unroll
    for (int e = 0; e < 8; e++) ss += s[c][e] * s[c][e];
  }
#pragma unroll
  for (int mm = 1; mm < 64; mm <<= 1) ss += __shfl_xor(ss, mm);
  __shared__ float wsum[4];
  if ((t & 63) == 0) wsum[t >> 6] = ss;
  __syncthreads();
  ss = wsum[0] + wsum[1] + wsum[2] + wsum[3];
  const float rs = rsqrtf(ss * (1.f / 4096.f) + 1e-5f);
#pragma unroll
  for (int c = 0; c < 2; c++) {
    const int base = c * 2048 + t * 8;
    const float4 wa = *(const float4*)&w[base];
    const float4 wb = *(const float4*)&w[base + 4];
    ushort ov[8];
    ov[0] = f2bf(s[c][0] * rs * wa.x); ov[1] = f2bf(s[c][1] * rs * wa.y);
    ov[2] = f2bf(s[c][2] * rs * wa.z); ov[3] = f2bf(s[c][3] * rs * wa.w);
    ov[4] = f2bf(s[c][4] * rs * wb.x); ov[5] = f2bf(s[c][5] * rs * wb.y);
    ov[6] = f2bf(s[c][6] * rs * wb.z); ov[7] = f2bf(s[c][7] * rs * wb.w);
    *(bf16x8*)&xn[rb + base] = *(bf16x8*)ov;
  }
}

// ---------------------------------------------------------------------------
// qk_addrope: q/k = rope(p0 + p1) on fp32 sums, written bf16 into qkv buffer.
// ---------------------------------------------------------------------------
__global__ __launch_bounds__(256)
void qk_addrope(const ushort* __restrict__ p0, const ushort* __restrict__ p1,
                ushort* __restrict__ qkv,
                const float* __restrict__ sinp, const float* __restrict__ cosp)
{
  const size_t idx = (size_t)blockIdx.x * 256 + threadIdx.x;   // < 2048*32*64
  const int d = (int)(idx & 63);
  const int h = (int)((idx >> 6) & 31);
  const int t = (int)(idx >> 11);
  const float s = sinp[t * 64 + d], c = cosp[t * 64 + d];
  const size_t qb = (size_t)t * QKV_N + h * HDIM + d;
  const size_t kb = qb + D_MODEL;
  const float q1 = bf2f(p0[qb])      + bf2f(p1[qb]);
  const float q2 = bf2f(p0[qb + 64]) + bf2f(p1[qb + 64]);
  qkv[qb]      = f2bf(q1 * c - q2 * s);
  qkv[qb + 64] = f2bf(q2 * c + q1 * s);
  const float k1 = bf2f(p0[kb])      + bf2f(p1[kb]);
  const float k2 = bf2f(p0[kb + 64]) + bf2f(p1[kb + 64]);
  qkv[kb]      = f2bf(k1 * c - k2 * s);
  qkv[kb + 64] = f2bf(k2 * c + k1 * s);
}

// ---------------------------------------------------------------------------
// Flash attention fwd. 1 wave per (b, h, 32-row Q pair). Deferred-max.
// ---------------------------------------------------------------------------
__global__ __launch_bounds__(64)
void attn_fwd(const ushort* __restrict__ q, const ushort* __restrict__ k,
              const ushort* __restrict__ vt, ushort* __restrict__ o,
              int ldq, int ldo)
{
  const int l = threadIdx.x, c16 = l & 15, g = l >> 4;
  const int qt = blockIdx.x, h = blockIdx.y, b = blockIdx.z;
  __shared__ __align__(16) ushort P_lds[2][16 * 32];

  const size_t head_off = (size_t)h * HDIM;
  const ushort* vtb = vt + (size_t)(b * NHEAD + h) * HDIM * SEQ;
  bf16x8 qf[2][4];
#pragma unroll
  for (int tile = 0; tile < 2; tile++) {
    const size_t rowQ = (size_t)(b * SEQ + qt * 32 + tile * 16 + c16);
#pragma unroll
    for (int kc = 0; kc < 4; kc++)
      qf[tile][kc] = *(const bf16x8*)(q + rowQ * ldq + head_off + kc * 32 + g * 8);
  }

  f32x4 oacc[2][8];
#pragma unroll
  for (int tile = 0; tile < 2; tile++)
#pragma unroll
    for (int i = 0; i < 8; i++) oacc[tile][i] = (f32x4){0.f, 0.f, 0.f, 0.f};
  float mrow[2][4], lsum[2][4];
#pragma unroll
  for (int tile = 0; tile < 2; tile++)
#pragma unroll
    for (int r = 0; r < 4; r++) { mrow[tile][r] = -1e30f; lsum[tile][r] = 0.f; }
  const float scale = 0.08838834764831845f;   // 1/sqrt(128)
  const float L2E = 1.4426950408889634f;

  for (int s0 = 0; s0 < SEQ; s0 += 32) {
    bf16x8 kfr[2][4];
#pragma unroll
    for (int t = 0; t < 2; t++) {
      const ushort* kb = k + (size_t)(b * SEQ + s0 + t * 16 + c16) * ldq + head_off + g * 8;
#pragma unroll
      for (int kc = 0; kc < 4; kc++) kfr[t][kc] = *(const bf16x8*)(kb + kc * 32);
    }
    f32x4 st[2][2];
#pragma unroll
    for (int tile = 0; tile < 2; tile++)
#pragma unroll
      for (int t = 0; t < 2; t++) {
        f32x4 a = (f32x4){0.f, 0.f, 0.f, 0.f};
#pragma unroll
        for (int kc = 0; kc < 4; kc++)
          a = __builtin_amdgcn_mfma_f32_16x16x32_bf16(qf[tile][kc], kfr[t][kc], a, 0, 0, 0);
        st[tile][t] = a;
      }

    float s0v[2][4], s1v[2][4];
    float worst = -1e30f;
#pragma unroll
    for (int tile = 0; tile < 2; tile++)
#pragma unroll
      for (int r = 0; r < 4; r++) {
        s0v[tile][r] = st[tile][0][r] * scale;
        s1v[tile][r] = st[tile][1][r] * scale;
        worst = fmaxf(worst, fmaxf(s0v[tile][r], s1v[tile][r]) - mrow[tile][r]);
      }

    if (__any(worst > 8.0f)) {
#pragma unroll
      for (int tile = 0; tile < 2; tile++) {
        float a4[4];
#pragma unroll
        for (int r = 0; r < 4; r++) {
          float cm = fmaxf(s0v[tile][r], s1v[tile][r]);
#pragma unroll
          for (int mm = 1; mm < 16; mm <<= 1) cm = fmaxf(cm, __shfl_xor(cm, mm));
          const float mn = fmaxf(mrow[tile][r], cm);
          a4[r] = exp2f((mrow[tile][r] - mn) * L2E);
          mrow[tile][r] = mn;
          const float p0 = exp2f((s0v[tile][r] - mn) * L2E);
          const float p1 = exp2f((s1v[tile][r] - mn) * L2E);
          lsum[tile][r] = lsum[tile][r] * a4[r] + p0 + p1;
          P_lds[tile][(g * 4 + r) * 32 + c16]      = f2bf(p0);
          P_lds[tile][(g * 4 + r) * 32 + 16 + c16] = f2bf(p1);
        }
        const f32x4 av = (f32x4){a4[0], a4[1], a4[2], a4[3]};
#pragma unroll
        for (int dbi = 0; dbi < 8; dbi++) oacc[tile][dbi] *= av;
      }
    } else {
#pragma unroll
      for (int tile = 0; tile < 2; tile++)
#pragma unroll
        for (int r = 0; r < 4; r++) {
          const float p0 = exp2f((s0v[tile][r] - mrow[tile][r]) * L2E);
          const float p1 = exp2f((s1v[tile][r] - mrow[tile][r]) * L2E);
          lsum[tile][r] += p0 + p1;
          P_lds[tile][(g * 4 + r) * 32 + c16]      = f2bf(p0);
          P_lds[tile][(g * 4 + r) * 32 + 16 + c16] = f2bf(p1);
        }
    }
    __syncthreads();
    const bf16x8 pf0 = *(const bf16x8*)&P_lds[0][c16 * 32 + g * 8];
    const bf16x8 pf1 = *(const bf16x8*)&P_lds[1][c16 * 32 + g * 8];
#pragma unroll
    for (int dbi = 0; dbi < 8; dbi++) {
      const bf16x8 vf = *(const bf16x8*)(vtb + (size_t)(dbi * 16 + c16) * SEQ + s0 + g * 8);
      oacc[0][dbi] = __builtin_amdgcn_mfma_f32_16x16x32_bf16(pf0, vf, oacc[0][dbi], 0, 0, 0);
      oacc[1][dbi] = __builtin_amdgcn_mfma_f32_16x16x32_bf16(pf1, vf, oacc[1][dbi], 0, 0, 0);
    }
    __syncthreads();
  }

#pragma unroll
  for (int tile = 0; tile < 2; tile++)
#pragma unroll
    for (int r = 0; r < 4; r++) {
#pragma unroll
      for (int mm = 1; mm < 16; mm <<= 1)
        lsum[tile][r] += __shfl_xor(lsum[tile][r], mm);
    }
#pragma unroll
  for (int tile = 0; tile < 2; tile++) {
    const size_t rowO = (size_t)(b * SEQ + qt * 32 + tile * 16 + g * 4);
#pragma unroll
    for (int dbi = 0; dbi < 8; dbi++)
#pragma unroll
      for (int r = 0; r < 4; r++)
        o[(rowO + r) * ldo + head_off + dbi * 16 + c16] =
            f2bf(oacc[tile][dbi][r] / lsum[tile][r]);
  }
}

// ---------------------------------------------------------------------------
// add3bf: d(fp32) = a(fp32) + p0(bf16) + p1(bf16).  Final out epilogue.
// ---------------------------------------------------------------------------
__global__ __launch_bounds__(256)
void add3bf_kernel(const float* __restrict__ a, const ushort* __restrict__ p0,
                   const ushort* __restrict__ p1, float* __restrict__ d, int n8)
{
  for (int i = blockIdx.x * 256 + threadIdx.x; i < n8; i += gridDim.x * 256) {
    const float4 a0 = ((const float4*)a)[i * 2];
    const float4 a1 = ((const float4*)a)[i * 2 + 1];
    const bf16x8 b = *(const bf16x8*)&p0[(size_t)i * 8];
    const bf16x8 c = *(const bf16x8*)&p1[(size_t)i * 8];
    float4 d0, d1;
    d0.x = a0.x + bf2f((ushort)b[0]) + bf2f((ushort)c[0]);
    d0.y = a0.y + bf2f((ushort)b[1]) + bf2f((ushort)c[1]);
    d0.z = a0.z + bf2f((ushort)b[2]) + bf2f((ushort)c[2]);
    d0.w = a0.w + bf2f((ushort)b[3]) + bf2f((ushort)c[3]);
    d1.x = a1.x + bf2f((ushort)b[4]) + bf2f((ushort)c[4]);
    d1.y = a1.y + bf2f((ushort)b[5]) + bf2f((ushort)c[5]);
    d1.z = a1.z + bf2f((ushort)b[6]) + bf2f((ushort)c[6]);
    d1.w = a1.w + bf2f((ushort)b[7]) + bf2f((ushort)c[7]);
    ((float4*)d)[i * 2]     = d0;
    ((float4*)d)[i * 2 + 1] = d1;
  }
}

// ---------------------------------------------------------------------------
// 256x256 GEMM, 3 phases/tile (16x16x32 MFMA, folded ds_read addressing).
// R14 ledger (verified): P1 stages A-h1(t+1)->P^1, P2 {A-h0,B-h0}(t+2)->P,
// P3 {B-h1}(t+2)->P, vmcnt(6) at tile end. Phase order: STG first, then
// ds_reads, LGKM0 (lgkm only), MFMA, [VMCNT6], SBAR.
// EPI 0: bf16 | 1: fp32 res+acc | 2: fused SwiGLU | 4: bf16 split-K partial.
// ---------------------------------------------------------------------------
template <int EPI, bool SPLITK>
__global__ __launch_bounds__(512, 2)
void gemm8p(const ushort* __restrict__ A, const ushort* __restrict__ Bt,
            const float* __restrict__ res, void* __restrict__ Cout,
            int M, int N, int Ks, int ldk, int wps)
{
  __shared__ __align__(16) ushort lds[65536];   // 128 KB
  const int tid = threadIdx.x;
  const int w = tid >> 6, l = tid & 63;
  const int c16 = l & 15, g = l >> 4;
  const int wr = w >> 2, wc = w & 3;

  // T1 bijective XCD remap (m204), then (optional) split-K, then 2D chunk
  const int nwg = gridDim.x;
  const int q8 = nwg >> 3, r8 = nwg & 7;
  const int xcd = blockIdx.x & 7, loc = blockIdx.x >> 3;
  int wg = (xcd < r8 ? xcd * (q8 + 1) : r8 * (q8 + 1) + (xcd - r8) * q8) + loc;
  int kslice = 0;
  if constexpr (SPLITK) { kslice = wg / wps; wg -= kslice * wps; }
  const size_t m0 = (size_t)(wg & 7) * 256;
  const size_t n0 = (size_t)(wg >> 3) * 256;
  const int nk = Ks >> 6;

  const int srow  = (w << 3) + (l >> 3);
  const int scolE = ((l & 7) ^ (l >> 3)) << 3;        // swizzled source col
  const ushort* gA = A  + (size_t)kslice * Ks + (m0 + srow) * (size_t)ldk + scolE;
  const ushort* gB = Bt + (size_t)kslice * Ks + (n0 + srow) * (size_t)ldk + scolE;

#define STG_A(p, h, q, tk)                                                        \
  gload_lds16(gA + (size_t)((h) * 128 + (q) * 64) * ldk + (size_t)(tk) * 64,      \
              lds + (p) * 16384 + (h) * 8192 + (q) * 4096 + (w << 9))
#define STG_B(p, h, q, tk)                                                        \
  gload_lds16(gB + (size_t)((h) * 128 + (q) * 64) * ldk + (size_t)(tk) * 64,      \
              lds + 32768 + (p) * 16384 + (h) * 8192 + (q) * 4096 + (w << 9))
#define STG_A2(p, h, tk) do { STG_A(p, h, 0, tk); STG_A(p, h, 1, tk); } while (0)
#define STG_B2(p, h, tk) do { STG_B(p, h, 0, tk); STG_B(p, h, 1, tk); } while (0)

  const int xorE = (c16 & 7) << 3;
  const int k0E = (g * 8) ^ xorE;
  const int k1E = (32 + g * 8) ^ xorE;
  const int aRow = wr * 64 + c16;
  const int bRow = wc * 32 + c16;

  const char* ldsb = (const char*)lds;
  const char* pA0 = ldsb + aRow * 128 + k0E * 2;
  const char* pA1 = ldsb + aRow * 128 + k1E * 2;
  const char* pB0 = ldsb + 65536 + bRow * 128 + k0E * 2;
  const char* pB1 = ldsb + 65536 + bRow * 128 + k1E * 2;

#define RDA(P, qm, i, kk)                                                         \
  (*(const bf16x8*)((kk ? pA1 : pA0) + (P) * 32768 + (qm) * 16384 + (i) * 2048))
#define RDB(P, qn, j, kk)                                                         \
  (*(const bf16x8*)((kk ? pB1 : pB0) + (P) * 32768 + (qn) * 16384 + (j) * 2048))

  f32x4 acc[8][4];
#pragma unroll
  for (int i = 0; i < 8; i++)
#pragma unroll
    for (int j = 0; j < 4; j++) acc[i][j] = (f32x4){0.f, 0.f, 0.f, 0.f};
  bf16x8 a[4][2], b0[2][2], b1[2][2];

  // prologue: tile 0 complete (8 loads), tile 1 minus A-h1 (6 loads)
  STG_A2(0, 0, 0); STG_A2(0, 1, 0); STG_B2(0, 0, 0); STG_B2(0, 1, 0);
  STG_A2(1, 0, 1); STG_B2(1, 0, 1); STG_B2(1, 1, 1);
  VMCNT6(); SBAR();

  auto tileBody = [&](auto Pc, int t) {
    constexpr int P = decltype(Pc)::value;
    const int tn1 = (t + 1 < nk) ? t + 1 : 0;             // wrap: garbage, never read
    const int tn2 = (t + 2 < nk) ? t + 2 : t + 2 - nk;

    // ---- phase 1: stage A-h1(t+1) -> buf P^1; rd b0+a0; MFMA Q(0,0)
    STG_A2(P ^ 1, 1, tn1);
#pragma unroll
    for (int j = 0; j < 2; ++j) { b0[j][0] = RDB(P, 0, j, 0); b0[j][1] = RDB(P, 0, j, 1); }
#pragma unroll
    for (int i = 0; i < 4; ++i) { a[i][0] = RDA(P, 0, i, 0); a[i][1] = RDA(P, 0, i, 1); }
    LGKM0();
    __builtin_amdgcn_s_setprio(1);
#pragma unroll
    for (int i = 0; i < 4; ++i)
#pragma unroll
      for (int j = 0; j < 2; ++j)
#pragma unroll
        for (int kk = 0; kk < 2; ++kk)
          acc[i][j] = __builtin_amdgcn_mfma_f32_16x16x32_bf16(a[i][kk], b0[j][kk], acc[i][j], 0, 0, 0);
    __builtin_amdgcn_s_setprio(0);
    SBAR();

    // ---- phase 2: stage {A-h0, B-h0}(t+2) -> buf P; rd b1; MFMA Q(0,1)
    STG_A2(P, 0, tn2);
    STG_B2(P, 0, tn2);
#pragma unroll
    for (int j = 0; j < 2; ++j) { b1[j][0] = RDB(P, 1, j, 0); b1[j][1] = RDB(P, 1, j, 1); }
    LGKM0();
    __builtin_amdgcn_s_setprio(1);
#pragma unroll
    for (int i = 0; i < 4; ++i)
#pragma unroll
      for (int j = 0; j < 2; ++j)
#pragma unroll
        for (int kk = 0; kk < 2; ++kk)
          acc[i][2 + j] = __builtin_amdgcn_mfma_f32_16x16x32_bf16(a[i][kk], b1[j][kk], acc[i][2 + j], 0, 0, 0);
    __builtin_amdgcn_s_setprio(0);
    SBAR();

    // ---- phase 3: stage {B-h1}(t+2) -> buf P; rd a1; MFMA Q(1,0)+Q(1,1); vmcnt(6)
    STG_B2(P, 1, tn2);
#pragma unroll
    for (int i = 0; i < 4; ++i) { a[i][0] = RDA(P, 1, i, 0); a[i][1] = RDA(P, 1, i, 1); }
    LGKM0();
    __builtin_amdgcn_s_setprio(1);
#pragma unroll
    for (int i = 0; i < 4; ++i)
#pragma unroll
      for (int j = 0; j < 2; ++j)
#pragma unroll
        for (int kk = 0; kk < 2; ++kk)
          acc[4 + i][j] = __builtin_amdgcn_mfma_f32_16x16x32_bf16(a[i][kk], b0[j][kk], acc[4 + i][j], 0, 0, 0);
#pragma unroll
    for (int i = 0; i < 4; ++i)
#pragma unroll
      for (int j = 0; j < 2; ++j)
#pragma unroll
        for (int kk = 0; kk < 2; ++kk)
          acc[4 + i][2 + j] = __builtin_amdgcn_mfma_f32_16x16x32_bf16(a[i][kk], b1[j][kk], acc[4 + i][2 + j], 0, 0, 0);
    __builtin_amdgcn_s_setprio(0);
    VMCNT6(); SBAR();
  };

  for (int t = 0; t < nk; t += 2) {                      // nk always even here
    tileBody(std::integral_constant<int, 0>{}, t);
    tileBody(std::integral_constant<int, 1>{}, t + 1);
  }

  // epilogue
#pragma unroll
  for (int qm = 0; qm < 2; qm++)
#pragma unroll
    for (int i = 0; i < 4; i++)
#pragma unroll
      for (int qn = 0; qn < 2; qn++)
#pragma unroll
        for (int j = 0; j < 2; j++)
#pragma unroll
          for (int r = 0; r < 4; r++) {
            const size_t row = m0 + qm * 128 + wr * 64 + i * 16 + g * 4 + r;
            if constexpr (EPI == 2) {
              if (qn == 1) continue;           // handled with qn==0 pair
              const float hv = acc[qm * 4 + i][j][r];
              const float uv = acc[qm * 4 + i][2 + j][r];
              const size_t col = (n0 >> 1) + wc * 32 + j * 16 + c16;
              ((ushort*)Cout)[row * (size_t)(N >> 1) + col] =
                  f2bf((hv / (1.f + __expf(-hv))) * uv);
            } else {
              const size_t col = n0 + qn * 128 + wc * 32 + j * 16 + c16;
              const size_t idx = row * N + col;
              const float v = acc[qm * 4 + i][qn * 2 + j][r];
              if constexpr (EPI == 0)      ((ushort*)Cout)[idx] = f2bf(v);
              else if constexpr (EPI == 1) ((float*)Cout)[idx] = res[idx] + v;
              else                         ((ushort*)Cout)[(size_t)kslice * M * N + idx] = f2bf(v);
            }
          }
#undef STG_A
#undef STG_B
#undef STG_A2
#undef STG_B2
#undef RDA
#undef RDB
}

// ---------------------------------------------------------------------------
extern "C" void kernel_launch(void* const* d_in, const int* in_sizes, int n_in,
                              void* d_out, int out_size, void* d_ws, size_t ws_size,
                              hipStream_t stream)
{
  const float* x    = (const float*)d_in[0];
  const float* sinp = (const float*)d_in[1];
  const float* cosp = (const float*)d_in[2];
  const float* anw  = (const float*)d_in[3];
  const float* fnw  = (const float*)d_in[4];
  const float* wq   = (const float*)d_in[5];
  const float* wk   = (const float*)d_in[6];
  const float* wv   = (const float*)d_in[7];
  const float* wo   = (const float*)d_in[8];
  const float* wff  = (const float*)d_in[9];
  const float* wup  = (const float*)d_in[10];
  const float* wout = (const float*)d_in[11];
  float* out = (float*)d_out;

  const size_t szDD   = (size_t)D_MODEL * D_MODEL * 2;
  const size_t szDF   = (size_t)D_MODEL * FF_DIM * 2;
  const size_t szAct2 = (size_t)M_ROWS * D_MODEL * 2;
  const size_t szAct4 = (size_t)M_ROWS * D_MODEL * 4;
  const size_t szQKV  = (size_t)M_ROWS * QKV_N * 2;
  const size_t MN     = (size_t)M_ROWS * D_MODEL;
  const size_t MNq    = (size_t)M_ROWS * QKV_N;

  char* ws = (char*)d_ws;
  size_t off = 0;
  auto alloc = [&](size_t bytes) -> char* {
    char* p = ws + off;
    off += (bytes + 255) & ~(size_t)255;
    return p;
  };
  ushort* R1    = (ushort*)alloc(szDF);     // wq|wk|wv^T, later wout^T
  ushort* R2    = (ushort*)alloc(2 * szDF); // qkv bf16 partials, then wff|wup panels
  ushort* wot   = (ushort*)alloc(szDD);
  ushort* xn    = (ushort*)alloc(szAct2);
  ushort* qkv   = (ushort*)alloc(szQKV);    // q,k roped; later reused as g
  ushort* attnb = (ushort*)alloc(szAct2);
  float*  x2    = (float*)alloc(szAct4);
  ushort* vtb   = (ushort*)alloc(szAct2);   // V^T [b,h,d,s]
  ushort* partb = (ushort*)alloc(2 * MN * 2); // bf16 split-K partials (N=4096 GEMMs)
  if (off > ws_size) return;                // visible failure, no corruption

  // attn-branch weights: one merged launch (R2 is qkv-partial scratch for now)
  conv_dd<<<dim3(D_MODEL / 64, D_MODEL / 64, 4), 256, 0, stream>>>(wq, wk, wv, wo, R1, wot);

  // attn branch
  rmsnorm_kernel<<<M_ROWS, 256, 0, stream>>>(x, anw, xn);
  // qkv GEMM: split-K x2 (Ks=2048), grid 768 = 3 full rounds; bf16 partials in R2
  ushort* qpart = R2;
  gemm8p<4, true><<<2 * (M_ROWS / 256) * (QKV_N / 256), 512, 0, stream>>>(
      xn, R1, nullptr, qpart, M_ROWS, QKV_N, D_MODEL / 2, D_MODEL,
      (M_ROWS / 256) * (QKV_N / 256));
  // fused epilogues consume the partials directly
  qk_addrope<<<(M_ROWS * NHEAD * 64) / 256, 256, 0, stream>>>(qpart, qpart + MNq, qkv, sinp, cosp);
  v_addtrans<<<dim3(M_ROWS / 32, HDIM / 32, NHEAD), dim3(32, 8), 0, stream>>>(qpart, qpart + MNq, vtb);

  // ffn weights now (R2 free again), wout into R1 (free after qkv GEMM)
  conv_ffup<<<dim3(FF_DIM / 64, D_MODEL / 64, 2), 256, 0, stream>>>(wff, wup, R2);
  transpose_convert<<<dim3(D_MODEL / 64, FF_DIM / 64), 256, 0, stream>>>(wout, R1, FF_DIM, D_MODEL);

  attn_fwd<<<dim3(SEQ / 32, NHEAD, NBATCH), 64, 0, stream>>>(qkv, qkv + D_MODEL, vtb, attnb, QKV_N, D_MODEL);
  // wo GEMM: split-K x2 (Ks=2048), bf16 partials -> rms_fuse makes x2 and xn
  gemm8p<4, true><<<256, 512, 0, stream>>>(attnb, wot, nullptr, partb, M_ROWS, D_MODEL, D_MODEL / 2, D_MODEL, 128);
  rms_fuse<<<M_ROWS, 256, 0, stream>>>(x, partb, partb + MN, fnw, x2, xn);

  // ffn branch (SwiGLU fused into GEMM epilogue; g written into qkv buffer)
  gemm8p<2, false><<<(M_ROWS / 256) * (FF2_N / 256), 512, 0, stream>>>(xn, R2, nullptr, qkv /* g */, M_ROWS, FF2_N, D_MODEL, D_MODEL, 0);
  // out GEMM: split-K x2 (Ks=6144), bf16 partials -> out = x2 + p0 + p1
  gemm8p<4, true><<<256, 512, 0, stream>>>(qkv, R1, nullptr, partb, M_ROWS, D_MODEL, FF_DIM / 2, FF_DIM, 128);
  add3bf_kernel<<<2048, 256, 0, stream>>>(x2, partb, partb + MN, out, (int)(MN / 8));
}